// Round 8
// baseline (33761.874 us; speedup 1.0000x reference)
//
#include <hip/hip_runtime.h>
#include <hip/hip_bf16.h>

#define B_SZ   256
#define T_SZ   256
#define FUT    32
#define TF_SZ  (T_SZ + FUT)
#define HIDN   1024
#define INDIM  64
#define OUTDIM 64
#define NBLK   256

typedef __attribute__((ext_vector_type(8))) short bf16x8;
typedef __attribute__((ext_vector_type(4))) float f32x4;

__device__ __forceinline__ float bf2f(unsigned short u) {
    union { unsigned int i; float f; } v; v.i = (unsigned int)u << 16; return v.f;
}
__device__ __forceinline__ unsigned short f2bf(float f) {
    union { float f; unsigned int i; } v; v.f = f;
    unsigned int r = v.i + 0x7FFFu + ((v.i >> 16) & 1u);
    return (unsigned short)(r >> 16);
}
__device__ __forceinline__ float sigm(float x) { return 1.0f / (1.0f + __expf(-x)); }

// Coherent (L2-bypassing, L3-served) 16B load as 2x u64 agent-scope atomics.
__device__ __forceinline__ bf16x8 ld_h(const unsigned short* p) {
    unsigned long long a = __hip_atomic_load((const unsigned long long*)p,
                                             __ATOMIC_RELAXED, __HIP_MEMORY_SCOPE_AGENT);
    unsigned long long b = __hip_atomic_load((const unsigned long long*)p + 1,
                                             __ATOMIC_RELAXED, __HIP_MEMORY_SCOPE_AGENT);
    union { unsigned long long q[2]; bf16x8 v; } u;
    u.q[0] = a; u.q[1] = b;
    return u.v;
}
// Coherent packed store of two adjacent bf16 (write-through, agent scope).
__device__ __forceinline__ void st_h2(unsigned short* p, unsigned short lo, unsigned short hi) {
    unsigned int w = (unsigned int)lo | ((unsigned int)hi << 16);
    __hip_atomic_store((unsigned int*)p, w, __ATOMIC_RELAXED, __HIP_MEMORY_SCOPE_AGENT);
}

// Grid barrier: NO cache maintenance. Monotone counter, relaxed atomics.
// h exchange is via sc1 atomics (L3-coherent), so only waitcnt + count order
// are needed. Workgroup fences = compiler ordering only (no wbl2/inv).
__device__ __forceinline__ void gbarrier(unsigned int* bar, unsigned int bidx) {
    __syncthreads();
    if (threadIdx.x == 0) {
        __builtin_amdgcn_fence(__ATOMIC_RELEASE, "workgroup");
        __builtin_amdgcn_s_waitcnt(0);                 // h stores acked at L3
        __hip_atomic_fetch_add(&bar[0], 1u, __ATOMIC_RELAXED,
                               __HIP_MEMORY_SCOPE_AGENT);
        const unsigned int tgt = bidx * (unsigned int)NBLK;
        while (__hip_atomic_load(&bar[0], __ATOMIC_RELAXED,
                                 __HIP_MEMORY_SCOPE_AGENT) < tgt)
            __builtin_amdgcn_s_sleep(1);
        __builtin_amdgcn_fence(__ATOMIC_ACQUIRE, "workgroup");
    }
    __syncthreads();
}

// ---------------------------------------------------------------------------
// Persistent 2-layer LSTM. 256 blocks x 512 threads (1 block/CU).
// Block owns 4 hidden units x 4 gates = 16 gate-rows (one A-fragment), all
// 256 batch rows. Weights register-resident (52 VGPR). Cell state in regs.
// All h / x-feedback traffic via agent-scope atomics (sc1) -> no fences.
// Merged superphase: {fold out(t-1) | L2(t) | L1(t+1)} -> 1 barrier/step.
// ---------------------------------------------------------------------------
__global__ __attribute__((amdgpu_flat_work_group_size(512, 512),
                          amdgpu_waves_per_eu(2, 2)))
void lstm_persist(
    const unsigned short* __restrict__ xbf,    // [256][256][64]
    unsigned short* __restrict__ xfut,         // [256][64]
    const unsigned short* __restrict__ W1,     // [4096][1088]
    const unsigned short* __restrict__ W2,     // [4096][2048]
    const unsigned short* __restrict__ Wlin,   // [64][1024]
    const unsigned short* __restrict__ Wo2i,   // [64][64]
    const float* __restrict__ b_ih1, const float* __restrict__ b_hh1,
    const float* __restrict__ b_ih2, const float* __restrict__ b_hh2,
    const float* __restrict__ blin, const float* __restrict__ bo2i,
    unsigned short* __restrict__ hh0,          // [256][2048] = [h1|h2]
    unsigned short* __restrict__ hh1,
    float* __restrict__ outp,                  // [256][288][64] f32
    unsigned int* __restrict__ bar)
{
    __shared__ float part[8][16][258];
    __shared__ float red[512];
    __shared__ float blds[32];

    const int tid  = threadIdx.x;
    const int id   = blockIdx.x;
    const int ug   = (id & 7) * 32 + (id >> 3);   // XCD-contiguous unit group
    const int jb   = ug * 4;
    const int ks   = tid >> 6;
    const int lane = tid & 63;
    const int am   = lane & 15, ah = lane >> 4;

    if (tid < 32) {
        const int L = tid >> 4, G = (tid >> 2) & 3, q = tid & 3;
        const int j = jb + q;
        blds[tid] = L ? (b_ih2[G * HIDN + j] + b_hh2[G * HIDN + j])
                      : (b_ih1[G * HIDN + j] + b_hh1[G * HIDN + j]);
    }

    const int wr = (am >> 2) * 1024 + jb + (am & 3);

    bf16x8 w2r[8];
    {
        const size_t b0 = (size_t)wr * 2048 + ks * 256 + ah * 8;
#pragma unroll
        for (int kk = 0; kk < 8; ++kk)
            w2r[kk] = *(const bf16x8*)(W2 + b0 + kk * 32);
    }
    const int kb1 = (ks < 2) ? ks * 160 : 320 + (ks - 2) * 128;
    const int kc1 = (ks < 2) ? 5 : 4;
    bf16x8 w1r[5];
#pragma unroll
    for (int kk = 0; kk < 5; ++kk) w1r[kk] = (bf16x8){0,0,0,0,0,0,0,0};
    {
        const size_t b0 = (size_t)wr * 1088 + kb1 + ah * 8;
#pragma unroll
        for (int kk = 0; kk < 5; ++kk) if (kk < kc1)
            w1r[kk] = *(const bf16x8*)(W1 + b0 + kk * 32);
    }

    // epilogue: thread handles units u0=2*jqA, u1=u0+1 for batch row bl
    const int jqA = tid >> 8;          // 0..1
    const int bl  = tid & 255;
    const int u0  = 2 * jqA, u1 = u0 + 1;
    float c1a = 0.f, c1b = 0.f, c2a = 0.f, c2b = 0.f;

    const int fc = id & 63, fq = id >> 6;
    const int frow = tid & 63, fkq = tid >> 6;
    __syncthreads();

    unsigned int bidx = 0;

    auto l1_phase = [&](const unsigned short* xsrc, const unsigned short* hsrc,
                        unsigned short* hdst) {
#pragma unroll 1
        for (int np = 0; np < 16; ++np) {
            const int brow = np * 16 + am;
            bf16x8 f[5];
#pragma unroll
            for (int kk = 0; kk < 5; ++kk) if (kk < kc1) {
                const int k = kb1 + kk * 32 + ah * 8;
                f[kk] = (k < 64)
                    ? ld_h(xsrc + (size_t)brow * INDIM + k)
                    : ld_h(hsrc + (size_t)brow * 2048 + (k - 64));
            }
            f32x4 pe = {0,0,0,0}, po = {0,0,0,0};
#pragma unroll
            for (int kk = 0; kk < 5; ++kk) if (kk < kc1) {
                if (kk & 1) po = __builtin_amdgcn_mfma_f32_16x16x32_bf16(w1r[kk], f[kk], po, 0, 0, 0);
                else        pe = __builtin_amdgcn_mfma_f32_16x16x32_bf16(w1r[kk], f[kk], pe, 0, 0, 0);
            }
#pragma unroll
            for (int r = 0; r < 4; ++r)
                part[ks][ah * 4 + r][np * 16 + am] = pe[r] + po[r];
        }
        __syncthreads();
        {
            float g0a = 0.f, g1a = 0.f, g2a = 0.f, g3a = 0.f;
            float g0b = 0.f, g1b = 0.f, g2b = 0.f, g3b = 0.f;
#pragma unroll
            for (int s = 0; s < 8; ++s) {
                g0a += part[s][u0][bl];      g1a += part[s][4 + u0][bl];
                g2a += part[s][8 + u0][bl];  g3a += part[s][12 + u0][bl];
                g0b += part[s][u1][bl];      g1b += part[s][4 + u1][bl];
                g2b += part[s][8 + u1][bl];  g3b += part[s][12 + u1][bl];
            }
            const float gia = sigm(g0a + blds[u0]),      gfa = sigm(g1a + blds[4 + u0]);
            const float gga = tanhf(g2a + blds[8 + u0]), goa = sigm(g3a + blds[12 + u0]);
            c1a = gfa * c1a + gia * gga;
            const float gib = sigm(g0b + blds[u1]),      gfb = sigm(g1b + blds[4 + u1]);
            const float ggb = tanhf(g2b + blds[8 + u1]), gob = sigm(g3b + blds[12 + u1]);
            c1b = gfb * c1b + gib * ggb;
            st_h2(hdst + (size_t)bl * 2048 + jb + u0,
                  f2bf(goa * tanhf(c1a)), f2bf(gob * tanhf(c1b)));
        }
        __syncthreads();
    };

    auto l2_phase = [&](const unsigned short* hsrc, unsigned short* hdst) {
#pragma unroll 1
        for (int np = 0; np < 16; ++np) {
            const int brow = np * 16 + am;
            const unsigned short* bp = hsrc + (size_t)brow * 2048 + ks * 256 + ah * 8;
            bf16x8 f[8];
#pragma unroll
            for (int kk = 0; kk < 8; ++kk)
                f[kk] = ld_h(bp + kk * 32);
            f32x4 pe = {0,0,0,0}, po = {0,0,0,0};
#pragma unroll
            for (int kk = 0; kk < 8; ++kk) {
                if (kk & 1) po = __builtin_amdgcn_mfma_f32_16x16x32_bf16(w2r[kk], f[kk], po, 0, 0, 0);
                else        pe = __builtin_amdgcn_mfma_f32_16x16x32_bf16(w2r[kk], f[kk], pe, 0, 0, 0);
            }
#pragma unroll
            for (int r = 0; r < 4; ++r)
                part[ks][ah * 4 + r][np * 16 + am] = pe[r] + po[r];
        }
        __syncthreads();
        {
            float g0a = 0.f, g1a = 0.f, g2a = 0.f, g3a = 0.f;
            float g0b = 0.f, g1b = 0.f, g2b = 0.f, g3b = 0.f;
#pragma unroll
            for (int s = 0; s < 8; ++s) {
                g0a += part[s][u0][bl];      g1a += part[s][4 + u0][bl];
                g2a += part[s][8 + u0][bl];  g3a += part[s][12 + u0][bl];
                g0b += part[s][u1][bl];      g1b += part[s][4 + u1][bl];
                g2b += part[s][8 + u1][bl];  g3b += part[s][12 + u1][bl];
            }
            const float gia = sigm(g0a + blds[16 + u0]),      gfa = sigm(g1a + blds[20 + u0]);
            const float gga = tanhf(g2a + blds[24 + u0]), goa = sigm(g3a + blds[28 + u0]);
            c2a = gfa * c2a + gia * gga;
            const float gib = sigm(g0b + blds[16 + u1]),      gfb = sigm(g1b + blds[20 + u1]);
            const float ggb = tanhf(g2b + blds[24 + u1]), gob = sigm(g3b + blds[28 + u1]);
            c2b = gfb * c2b + gib * ggb;
            st_h2(hdst + (size_t)bl * 2048 + 1024 + jb + u0,
                  f2bf(goa * tanhf(c2a)), f2bf(gob * tanhf(c2b)));
        }
        __syncthreads();
    };

    auto fold = [&](int tm1, const unsigned short* hsrc) {
        const unsigned short* hp = hsrc + (size_t)(fq * 64 + frow) * 2048 + 1024 + fkq * 128;
        const unsigned short* wp = Wlin + (size_t)fc * 1024 + fkq * 128;
        float p = 0.f;
#pragma unroll
        for (int k = 0; k < 128; k += 8) {
            bf16x8 hv = ld_h(hp + k);
            bf16x8 wv = *(const bf16x8*)(wp + k);
#pragma unroll
            for (int u = 0; u < 8; ++u)
                p += bf2f((unsigned short)hv[u]) * bf2f((unsigned short)wv[u]);
        }
        red[fkq * 64 + frow] = p;
        __syncthreads();
        if (tid < 64) {
            float s = blin[fc];
#pragma unroll
            for (int u = 0; u < 8; ++u) s += red[u * 64 + tid];
            outp[((size_t)(fq * 64 + tid) * TF_SZ + tm1) * OUTDIM + fc] = s;
        }
        __syncthreads();
    };

    auto tail_out = [&](int t, const unsigned short* hnew, int do_fb) {
        if (id < 32) {
            unsigned short* h2s = (unsigned short*)&part[0][0][0];  // [8][1024]
            float* xstage = (float*)((char*)&part[0][0][0] + 16384); // [8][64]
            const int rowbase = id * 8;
            for (int i = tid; i < 1024; i += 512) {
                const int rr = i >> 7, k8 = (i & 127) * 8;
                bf16x8 hv = ld_h(hnew + (size_t)(rowbase + rr) * 2048 + 1024 + k8);
                *(bf16x8*)&h2s[rr * 1024 + k8] = hv;
            }
            __syncthreads();
            const int rl = tid >> 6, col = tid & 63;
            float acc = blin[col];
            const unsigned short* wl = Wlin + (size_t)col * HIDN;
            for (int k = 0; k < HIDN; k += 8) {
                bf16x8 hv = *(const bf16x8*)&h2s[rl * 1024 + k];
                bf16x8 wv = *(const bf16x8*)&wl[k];
#pragma unroll
                for (int u = 0; u < 8; ++u)
                    acc += bf2f((unsigned short)hv[u]) * bf2f((unsigned short)wv[u]);
            }
            outp[((size_t)(rowbase + rl) * TF_SZ + t) * OUTDIM + col] = acc;
            if (do_fb) {
                red[rl * 64 + col] = acc;
                __syncthreads();
                float x = bo2i[col];
                const unsigned short* w2 = Wo2i + (size_t)col * OUTDIM;
#pragma unroll 8
                for (int jj = 0; jj < OUTDIM; ++jj)
                    x += red[rl * 64 + jj] * bf2f(w2[jj]);
                xstage[rl * 64 + col] = x;
                __syncthreads();
                if (col < 32) {
                    st_h2(xfut + (size_t)(rowbase + rl) * INDIM + col * 2,
                          f2bf(xstage[rl * 64 + col * 2]),
                          f2bf(xstage[rl * 64 + col * 2 + 1]));
                }
            }
        }
    };

    // ================= schedule =================
    l1_phase(xbf, hh0, hh1);
    gbarrier(bar, ++bidx);

    for (int t = 0; t < T_SZ - 1; ++t) {
        const unsigned short* hsrc = ((t + 1) & 1) ? hh1 : hh0;
        unsigned short*       hdst = (t & 1) ? hh1 : hh0;
        if (t >= 1) fold(t - 1, hsrc);
        l2_phase(hsrc, hdst);
        l1_phase(xbf + (size_t)(t + 1) * B_SZ * INDIM, hsrc, hdst);
        gbarrier(bar, ++bidx);
    }

    for (int t = T_SZ - 1; t < TF_SZ; ++t) {
        const unsigned short* hsrc = ((t + 1) & 1) ? hh1 : hh0;
        unsigned short*       hdst = (t & 1) ? hh1 : hh0;
        if (t == T_SZ - 1) fold(t - 1, hsrc);
        l2_phase(hsrc, hdst);
        gbarrier(bar, ++bidx);
        tail_out(t, hdst, t < TF_SZ - 1);
        if (t < TF_SZ - 1) {
            gbarrier(bar, ++bidx);
            l1_phase(xfut, hsrc, hdst);
            gbarrier(bar, ++bidx);
        }
    }
}

__global__ void conv_strided(const float* __restrict__ src,
                             unsigned short* __restrict__ dst,
                             int cols, int dstride, int doff, int total)
{
    const int idx = blockIdx.x * 256 + threadIdx.x;
    if (idx >= total) return;
    const int r = idx / cols, c = idx - r * cols;
    dst[(size_t)r * dstride + doff + c] = f2bf(src[idx]);
}

__global__ void conv_x(const float* __restrict__ src,
                       unsigned short* __restrict__ dst)
{
    const int idx = blockIdx.x * 256 + threadIdx.x;
    const int f = idx & 63, t = (idx >> 6) & 255, b = idx >> 14;
    dst[((size_t)t * B_SZ + b) * INDIM + f] = f2bf(src[idx]);
}

extern "C" void kernel_launch(void* const* d_in, const int* in_sizes, int n_in,
                              void* d_out, int out_size, void* d_ws, size_t ws_size,
                              hipStream_t stream)
{
    const float* input = (const float*)d_in[0];
    const float* W_ih1 = (const float*)d_in[1];
    const float* W_hh1 = (const float*)d_in[2];
    const float* b_ih1 = (const float*)d_in[3];
    const float* b_hh1 = (const float*)d_in[4];
    const float* W_ih2 = (const float*)d_in[5];
    const float* W_hh2 = (const float*)d_in[6];
    const float* b_ih2 = (const float*)d_in[7];
    const float* b_hh2 = (const float*)d_in[8];
    const float* W_lin = (const float*)d_in[9];
    const float* b_lin = (const float*)d_in[10];
    const float* W_o2i = (const float*)d_in[11];
    const float* b_o2i = (const float*)d_in[12];
    float* outp = (float*)d_out;

    char* ws = (char*)d_ws;
    unsigned short* Wcat1 = (unsigned short*)ws; ws += (size_t)4096 * 1088 * 2;
    unsigned short* Wcat2 = (unsigned short*)ws; ws += (size_t)4096 * 2048 * 2;
    unsigned short* Wlinb = (unsigned short*)ws; ws += (size_t)64 * 1024 * 2;
    unsigned short* Wo2ib = (unsigned short*)ws; ws += (size_t)64 * 64 * 2;
    unsigned short* xbf   = (unsigned short*)ws; ws += (size_t)T_SZ * B_SZ * INDIM * 2;
    unsigned short* hh0   = (unsigned short*)ws; ws += (size_t)B_SZ * 2 * HIDN * 2;
    unsigned short* hh1   = (unsigned short*)ws; ws += (size_t)B_SZ * 2 * HIDN * 2;
    unsigned short* xfut  = (unsigned short*)ws; ws += (size_t)B_SZ * INDIM * 2;
    ws = (char*)(((size_t)ws + 255) & ~(size_t)255);
    unsigned int*   bar   = (unsigned int*)ws;   ws += 256;

    conv_strided<<<(4096 * 64 + 255) / 256, 256, 0, stream>>>(W_ih1, Wcat1, 64, 1088, 0, 4096 * 64);
    conv_strided<<<(4096 * 1024 + 255) / 256, 256, 0, stream>>>(W_hh1, Wcat1, 1024, 1088, 64, 4096 * 1024);
    conv_strided<<<(4096 * 1024 + 255) / 256, 256, 0, stream>>>(W_ih2, Wcat2, 1024, 2048, 0, 4096 * 1024);
    conv_strided<<<(4096 * 1024 + 255) / 256, 256, 0, stream>>>(W_hh2, Wcat2, 1024, 2048, 1024, 4096 * 1024);
    conv_strided<<<(64 * 1024 + 255) / 256, 256, 0, stream>>>(W_lin, Wlinb, 1024, 1024, 0, 64 * 1024);
    conv_strided<<<(64 * 64 + 255) / 256, 256, 0, stream>>>(W_o2i, Wo2ib, 64, 64, 0, 64 * 64);
    conv_x<<<(T_SZ * B_SZ * INDIM) / 256, 256, 0, stream>>>(input, xbf);

    hipMemsetAsync(hh0, 0, (size_t)B_SZ * 2 * HIDN * 2, stream);
    hipMemsetAsync(hh1, 0, (size_t)B_SZ * 2 * HIDN * 2, stream);
    hipMemsetAsync(bar, 0, 256, stream);

    void* kargs[] = {
        (void*)&xbf, (void*)&xfut, (void*)&Wcat1, (void*)&Wcat2,
        (void*)&Wlinb, (void*)&Wo2ib,
        (void*)&b_ih1, (void*)&b_hh1, (void*)&b_ih2, (void*)&b_hh2,
        (void*)&b_lin, (void*)&b_o2i,
        (void*)&hh0, (void*)&hh1, (void*)&outp, (void*)&bar
    };
    hipLaunchCooperativeKernel((void*)lstm_persist, dim3(NBLK), dim3(512),
                               kargs, 0, stream);
}